// Round 10
// baseline (294.054 us; speedup 1.0000x reference)
//
#include <hip/hip_runtime.h>
#include <hip/hip_bf16.h>

#define BATCH 1024
#define SEQ 256
#define HIDDEN 128
#define VOCAB 60
#define MTILE 16
#define NTILES 2           // two independent 16-row tiles per block
#define ASTRIDE 136        // f16 per h row: 128+8 pad (68 dw == 4 mod 32 -> 2-way on b128, free)
#define EWSTRIDE 132       // f16 per ew row: 66 dw == 2 mod 32 -> random-token b64 gather spreads 16 bank groups; 264B keeps 8B align

typedef _Float16 f16x8 __attribute__((ext_vector_type(8)));
typedef _Float16 f16x4 __attribute__((ext_vector_type(4)));
typedef float f32x4 __attribute__((ext_vector_type(4)));

__device__ __forceinline__ float fast_tanh(float x) {
    // tanh(x) = 1 - 2/(exp(2x)+1); exp(2x)=exp2(x*2*log2e). Branch-free, exact +-1 tails.
    float e = __builtin_amdgcn_exp2f(x * 2.8853900817779268f);
    return __builtin_fmaf(-2.0f, __builtin_amdgcn_rcpf(e + 1.0f), 1.0f);
}

// embW[v][i] = sum_j emb[v][j] * W_ih[i][j]  (fp32-exact input-projection table)
__global__ void rnn_prep_embw(const float* __restrict__ emb,
                              const float* __restrict__ W_ih,
                              float* __restrict__ embW) {
    const int v = blockIdx.x;
    const int i = threadIdx.x;
    __shared__ __align__(16) float e[HIDDEN];
    e[i] = emb[v * HIDDEN + i];
    __syncthreads();
    const float4* wrow = (const float4*)(W_ih + i * HIDDEN);
    const float4* e4 = (const float4*)e;
    float a0 = 0.f, a1 = 0.f, a2 = 0.f, a3 = 0.f;
#pragma unroll
    for (int j = 0; j < HIDDEN / 4; ++j) {
        float4 w = wrow[j];
        float4 h = e4[j];
        a0 += w.x * h.x; a1 += w.y * h.y; a2 += w.z * h.z; a3 += w.w * h.w;
    }
    embW[v * HIDDEN + i] = (a0 + a1) + (a2 + a3);
}

// 32 blocks x 4 waves (256 thr). Each block: TWO independent 16-row tiles.
// Wave w owns z-cols [32w,32w+32) of BOTH tiles (same W_hh frags, 32 VGPRs).
// Transposed recurrence z^T = W_hh * h^T per tile. One barrier per region
// covers both tile-steps; the two streams are independent so reads/MFMA/tanh
// of one overlap the other's latency. Seeds from LDS ew (stride-132), tokens
// from global prefetched 2 steps ahead.
__global__ void __launch_bounds__(256)
rnn_mfma(const int* __restrict__ x, const int* __restrict__ lengths,
         const float* __restrict__ embW, const float* __restrict__ W_hh,
         const float* __restrict__ W_fc, const float* __restrict__ b_fc,
         float* __restrict__ out) {
    const int tid = threadIdx.x;
    const int wave = tid >> 6;   // 0..3
    const int lane = tid & 63;
    const int q = lane >> 4;     // 0..3
    const int r16 = lane & 15;   // batch row within tile
    const int c0 = wave * 32;    // wave's z-col base (32 cols = 2 M-tiles)
    const int b0 = blockIdx.x * (NTILES * MTILE);
    const int rowA = b0 + r16;
    const int rowB = b0 + MTILE + r16;

    __shared__ __align__(16) _Float16 Ah[2][NTILES][MTILE][ASTRIDE];  // 17408 B
    __shared__ __align__(16) _Float16 ew[VOCAB][EWSTRIDE];            // 15840 B
    __shared__ __align__(16) float hfin[NTILES * MTILE][HIDDEN];      // 16384 B
    __shared__ int lenbuf[NTILES * MTILE];

    // Stage ew (f32->f16), lengths; zero both h buffers.
    for (int idx = tid; idx < VOCAB * HIDDEN; idx += 256) {
        int v = idx >> 7, c = idx & 127;
        ew[v][c] = (_Float16)embW[idx];
    }
    if (tid < NTILES * MTILE) lenbuf[tid] = lengths[b0 + tid];
    for (int idx = tid; idx < (int)(sizeof(Ah) / 4); idx += 256)
        ((int*)Ah)[idx] = 0;

    // Static A-frags of W_hh: lane holds A[m=r16][k=q*8+j] for M-tile nt:
    // W_hh[c0 + 16*nt + r16][kc*32 + q*8 + j].  32 VGPRs, shared by both tiles.
    f16x8 Wf[2][4];
#pragma unroll
    for (int nt = 0; nt < 2; ++nt) {
        const float* wrow = W_hh + (c0 + 16 * nt + r16) * HIDDEN + q * 8;
#pragma unroll
        for (int kc = 0; kc < 4; ++kc) {
            const float* p = wrow + kc * 32;
#pragma unroll
            for (int j = 0; j < 8; ++j) Wf[nt][kc][j] = (_Float16)p[j];
        }
    }

    __syncthreads();

    const int mylenA = lenbuf[r16];
    const int mylenB = lenbuf[MTILE + r16];
    int lenmax = 0;
#pragma unroll
    for (int r = 0; r < NTILES * MTILE; ++r) lenmax = max(lenmax, lenbuf[r]);

    // Token / seed pipeline. Seeds for step t prefetched during step t-1 from
    // LDS ew; tokens for t+2 prefetched from global (2-step latency span).
    const int* xrowA = x + rowA * SEQ;
    const int* xrowB = x + rowB * SEQ;
    int tokA = xrowA[0], tokB = xrowB[0];
    f16x4 sA0 = *(const f16x4*)&ew[tokA][c0 + 4 * q];
    f16x4 sA1 = *(const f16x4*)&ew[tokA][c0 + 16 + 4 * q];
    f16x4 sB0 = *(const f16x4*)&ew[tokB][c0 + 4 * q];
    f16x4 sB1 = *(const f16x4*)&ew[tokB][c0 + 16 + 4 * q];
    int tokA1 = xrowA[1], tokB1 = xrowB[1];  // SEQ >= 2 always

    int cur = 0;
    uint2 capA0 = {0u, 0u}, capA1 = {0u, 0u}, capB0 = {0u, 0u}, capB1 = {0u, 0u};

    for (int t = 0; t < lenmax; ++t) {
        // --- reads: both tiles up front (independent streams) ---
        const _Float16* hbA = &Ah[cur][0][r16][q * 8];
        f16x8 HA0 = *(const f16x8*)(hbA + 0);
        f16x8 HA1 = *(const f16x8*)(hbA + 32);
        f16x8 HA2 = *(const f16x8*)(hbA + 64);
        f16x8 HA3 = *(const f16x8*)(hbA + 96);
        const _Float16* hbB = &Ah[cur][1][r16][q * 8];
        f16x8 HB0 = *(const f16x8*)(hbB + 0);
        f16x8 HB1 = *(const f16x8*)(hbB + 32);
        f16x8 HB2 = *(const f16x8*)(hbB + 64);
        f16x8 HB3 = *(const f16x8*)(hbB + 96);

        // Seed prefetch for t+1 (LDS, static table).
        f16x4 snA0 = *(const f16x4*)&ew[tokA1][c0 + 4 * q];
        f16x4 snA1 = *(const f16x4*)&ew[tokA1][c0 + 16 + 4 * q];
        f16x4 snB0 = *(const f16x4*)&ew[tokB1][c0 + 4 * q];
        f16x4 snB1 = *(const f16x4*)&ew[tokB1][c0 + 16 + 4 * q];

        // Token prefetch for t+2 (global; drained only at region barrier).
        const int t2 = (t + 2 < SEQ) ? t + 2 : SEQ - 1;
        const int tokA2 = xrowA[t2];
        const int tokB2 = xrowB[t2];

        // --- MFMA: per tile 4 indep 2-deep chains ---
        f32x4 aA0 = {(float)sA0[0], (float)sA0[1], (float)sA0[2], (float)sA0[3]};
        f32x4 aA1 = {(float)sA1[0], (float)sA1[1], (float)sA1[2], (float)sA1[3]};
        f32x4 dA0 = {0.f, 0.f, 0.f, 0.f}, dA1 = {0.f, 0.f, 0.f, 0.f};
        f32x4 aB0 = {(float)sB0[0], (float)sB0[1], (float)sB0[2], (float)sB0[3]};
        f32x4 aB1 = {(float)sB1[0], (float)sB1[1], (float)sB1[2], (float)sB1[3]};
        f32x4 dB0 = {0.f, 0.f, 0.f, 0.f}, dB1 = {0.f, 0.f, 0.f, 0.f};

        aA0 = __builtin_amdgcn_mfma_f32_16x16x32_f16(Wf[0][0], HA0, aA0, 0, 0, 0);
        aA1 = __builtin_amdgcn_mfma_f32_16x16x32_f16(Wf[1][0], HA0, aA1, 0, 0, 0);
        aB0 = __builtin_amdgcn_mfma_f32_16x16x32_f16(Wf[0][0], HB0, aB0, 0, 0, 0);
        aB1 = __builtin_amdgcn_mfma_f32_16x16x32_f16(Wf[1][0], HB0, aB1, 0, 0, 0);
        dA0 = __builtin_amdgcn_mfma_f32_16x16x32_f16(Wf[0][2], HA2, dA0, 0, 0, 0);
        dA1 = __builtin_amdgcn_mfma_f32_16x16x32_f16(Wf[1][2], HA2, dA1, 0, 0, 0);
        dB0 = __builtin_amdgcn_mfma_f32_16x16x32_f16(Wf[0][2], HB2, dB0, 0, 0, 0);
        dB1 = __builtin_amdgcn_mfma_f32_16x16x32_f16(Wf[1][2], HB2, dB1, 0, 0, 0);
        aA0 = __builtin_amdgcn_mfma_f32_16x16x32_f16(Wf[0][1], HA1, aA0, 0, 0, 0);
        aA1 = __builtin_amdgcn_mfma_f32_16x16x32_f16(Wf[1][1], HA1, aA1, 0, 0, 0);
        aB0 = __builtin_amdgcn_mfma_f32_16x16x32_f16(Wf[0][1], HB1, aB0, 0, 0, 0);
        aB1 = __builtin_amdgcn_mfma_f32_16x16x32_f16(Wf[1][1], HB1, aB1, 0, 0, 0);
        dA0 = __builtin_amdgcn_mfma_f32_16x16x32_f16(Wf[0][3], HA3, dA0, 0, 0, 0);
        dA1 = __builtin_amdgcn_mfma_f32_16x16x32_f16(Wf[1][3], HA3, dA1, 0, 0, 0);
        dB0 = __builtin_amdgcn_mfma_f32_16x16x32_f16(Wf[0][3], HB3, dB0, 0, 0, 0);
        dB1 = __builtin_amdgcn_mfma_f32_16x16x32_f16(Wf[1][3], HB3, dB1, 0, 0, 0);

        f32x4 zA0 = aA0 + dA0, zA1 = aA1 + dA1;
        f32x4 zB0 = aB0 + dB0, zB1 = aB1 + dB1;

        // --- tanh + pack + capture + write, tile A then tile B ---
        const int nxt = cur ^ 1;
        {
            float u0 = fast_tanh(zA0[0]), u1 = fast_tanh(zA0[1]);
            float u2 = fast_tanh(zA0[2]), u3 = fast_tanh(zA0[3]);
            float v0 = fast_tanh(zA1[0]), v1 = fast_tanh(zA1[1]);
            float v2 = fast_tanh(zA1[2]), v3 = fast_tanh(zA1[3]);
            uint2 p0, p1;
            p0.x = __builtin_bit_cast(unsigned int, __builtin_amdgcn_cvt_pkrtz(u0, u1));
            p0.y = __builtin_bit_cast(unsigned int, __builtin_amdgcn_cvt_pkrtz(u2, u3));
            p1.x = __builtin_bit_cast(unsigned int, __builtin_amdgcn_cvt_pkrtz(v0, v1));
            p1.y = __builtin_bit_cast(unsigned int, __builtin_amdgcn_cvt_pkrtz(v2, v3));
            if (t + 1 == mylenA) { capA0 = p0; capA1 = p1; }
            *(uint2*)&Ah[nxt][0][r16][c0 + 4 * q] = p0;
            *(uint2*)&Ah[nxt][0][r16][c0 + 16 + 4 * q] = p1;
        }
        {
            float u0 = fast_tanh(zB0[0]), u1 = fast_tanh(zB0[1]);
            float u2 = fast_tanh(zB0[2]), u3 = fast_tanh(zB0[3]);
            float v0 = fast_tanh(zB1[0]), v1 = fast_tanh(zB1[1]);
            float v2 = fast_tanh(zB1[2]), v3 = fast_tanh(zB1[3]);
            uint2 p0, p1;
            p0.x = __builtin_bit_cast(unsigned int, __builtin_amdgcn_cvt_pkrtz(u0, u1));
            p0.y = __builtin_bit_cast(unsigned int, __builtin_amdgcn_cvt_pkrtz(u2, u3));
            p1.x = __builtin_bit_cast(unsigned int, __builtin_amdgcn_cvt_pkrtz(v0, v1));
            p1.y = __builtin_bit_cast(unsigned int, __builtin_amdgcn_cvt_pkrtz(v2, v3));
            if (t + 1 == mylenB) { capB0 = p0; capB1 = p1; }
            *(uint2*)&Ah[nxt][1][r16][c0 + 4 * q] = p0;
            *(uint2*)&Ah[nxt][1][r16][c0 + 16 + 4 * q] = p1;
        }
        __syncthreads();
        cur = nxt;
        sA0 = snA0; sA1 = snA1; sB0 = snB0; sB1 = snB1;
        tokA1 = tokA2; tokB1 = tokB2;
    }

    // Final h (f16-rounded caps -> f32) into hfin, then FC epilogue.
    {
        f16x4 a0 = __builtin_bit_cast(f16x4, capA0), a1 = __builtin_bit_cast(f16x4, capA1);
        f16x4 b0c = __builtin_bit_cast(f16x4, capB0), b1c = __builtin_bit_cast(f16x4, capB1);
#pragma unroll
        for (int v = 0; v < 4; ++v) {
            hfin[r16][c0 + 4 * q + v] = (float)a0[v];
            hfin[r16][c0 + 16 + 4 * q + v] = (float)a1[v];
            hfin[MTILE + r16][c0 + 4 * q + v] = (float)b0c[v];
            hfin[MTILE + r16][c0 + 16 + 4 * q + v] = (float)b1c[v];
        }
    }
    __syncthreads();

    // FC: 256 threads = 32 rows x 8 vocab slots.
    const int r = tid >> 3;      // 0..31
    const int vb = tid & 7;      // 0..7
    const float4* hv = (const float4*)hfin[r];
    for (int vo = vb; vo < VOCAB; vo += 8) {
        const float4* wf = (const float4*)(W_fc + vo * HIDDEN);
        float a0 = 0.f, a1 = 0.f, a2 = 0.f, a3 = 0.f;
#pragma unroll
        for (int j = 0; j < HIDDEN / 4; ++j) {
            float4 a = hv[j];
            float4 w = wf[j];
            a0 += a.x * w.x; a1 += a.y * w.y; a2 += a.z * w.z; a3 += a.w * w.w;
        }
        out[(b0 + r) * VOCAB + vo] = (a0 + a1) + (a2 + a3) + b_fc[vo];
    }
}

extern "C" void kernel_launch(void* const* d_in, const int* in_sizes, int n_in,
                              void* d_out, int out_size, void* d_ws, size_t ws_size,
                              hipStream_t stream) {
    const int* x = (const int*)d_in[0];          // [B, T] int32
    const int* lengths = (const int*)d_in[1];    // [B] int32
    const float* emb = (const float*)d_in[2];    // [V, H]
    const float* W_ih = (const float*)d_in[3];   // [H, H]
    const float* W_hh = (const float*)d_in[4];   // [H, H]
    const float* W_fc = (const float*)d_in[5];   // [V, H]
    const float* b_fc = (const float*)d_in[6];   // [V]
    float* out = (float*)d_out;                  // [B, V]

    float* embW = (float*)d_ws;                  // VOCAB*HIDDEN floats (30 KB)

    rnn_prep_embw<<<VOCAB, HIDDEN, 0, stream>>>(emb, W_ih, embW);
    rnn_mfma<<<BATCH / (NTILES * MTILE), 256, 0, stream>>>(x, lengths, embW, W_hh, W_fc, b_fc, out);
}

// Round 11
// 173.733 us; speedup vs baseline: 1.6926x; 1.6926x over previous
//
#include <hip/hip_runtime.h>
#include <hip/hip_bf16.h>

#define BATCH 1024
#define SEQ 256
#define HIDDEN 128
#define VOCAB 60
#define ROWS 4             // real batch rows per block (16-row MFMA n-dim aliased 4x)
#define ASTRIDE 136        // f16 per h row: 128+8 pad
#define EWSTRIDE 132       // f16 per ew row: 66 dw == 2 mod 32 spreads random-token gathers

typedef _Float16 f16x8 __attribute__((ext_vector_type(8)));
typedef _Float16 f16x4 __attribute__((ext_vector_type(4)));
typedef float f32x4 __attribute__((ext_vector_type(4)));

__device__ __forceinline__ float fast_tanh(float x) {
    // tanh(x) = 1 - 2/(exp(2x)+1); exp(2x)=exp2(x*2*log2e). Branch-free, exact +-1 tails.
    float e = __builtin_amdgcn_exp2f(x * 2.8853900817779268f);
    return __builtin_fmaf(-2.0f, __builtin_amdgcn_rcpf(e + 1.0f), 1.0f);
}

// embW[v][i] = sum_j emb[v][j] * W_ih[i][j]  (fp32-exact input-projection table)
__global__ void rnn_prep_embw(const float* __restrict__ emb,
                              const float* __restrict__ W_ih,
                              float* __restrict__ embW) {
    const int v = blockIdx.x;
    const int i = threadIdx.x;
    __shared__ __align__(16) float e[HIDDEN];
    e[i] = emb[v * HIDDEN + i];
    __syncthreads();
    const float4* wrow = (const float4*)(W_ih + i * HIDDEN);
    const float4* e4 = (const float4*)e;
    float a0 = 0.f, a1 = 0.f, a2 = 0.f, a3 = 0.f;
#pragma unroll
    for (int j = 0; j < HIDDEN / 4; ++j) {
        float4 w = wrow[j];
        float4 h = e4[j];
        a0 += w.x * h.x; a1 += w.y * h.y; a2 += w.z * h.z; a3 += w.w * h.w;
    }
    embW[v * HIDDEN + i] = (a0 + a1) + (a2 + a3);
}

// 256 blocks x 512 threads (8 waves, 2/SIMD). Each block owns 4 batch rows.
// Transposed recurrence z^T = W_hh * h^T; wave w owns z-cols [16w,16w+16).
// The MFMA B-operand n-dim (16) is fed with the 4 real rows aliased 4x
// (r16 & 3): same-address lanes broadcast (free), duplicated rows evolve
// bitwise-identically (same tokens, same W). Writes guarded to r16<4.
// All K-loop traffic is LDS; one barrier per step.
__global__ void __launch_bounds__(512)
rnn_mfma(const int* __restrict__ x, const int* __restrict__ lengths,
         const float* __restrict__ embW, const float* __restrict__ W_hh,
         const float* __restrict__ W_fc, const float* __restrict__ b_fc,
         float* __restrict__ out) {
    const int tid = threadIdx.x;
    const int wave = tid >> 6;   // 0..7
    const int lane = tid & 63;
    const int q = lane >> 4;     // 0..3 (k-group for A/B frags; reg-group for C rows)
    const int r16 = lane & 15;   // MFMA n index
    const int r4 = r16 & 3;      // real batch row (aliased 4x)
    const int c0 = wave * 16;    // wave's z-col base
    const int b0 = blockIdx.x * ROWS;

    __shared__ __align__(16) _Float16 Ah[2][ROWS][ASTRIDE];   // 2176 B
    __shared__ __align__(16) _Float16 ew[VOCAB][EWSTRIDE];    // 15840 B
    __shared__ int xs[ROWS][SEQ + 1];                         // 4112 B
    __shared__ __align__(16) float hfin[ROWS][HIDDEN];        // 2048 B
    __shared__ int lenbuf[ROWS];

    // Stage: ew (f32->f16), tokens, lengths; zero both h buffers.
    for (int idx = tid; idx < VOCAB * HIDDEN; idx += 512) {
        int v = idx >> 7, c = idx & 127;
        ew[v][c] = (_Float16)embW[idx];
    }
    for (int idx = tid; idx < ROWS * SEQ; idx += 512) {
        int r = idx >> 8, t = idx & (SEQ - 1);
        xs[r][t] = x[(b0 + r) * SEQ + t];
    }
    if (tid < ROWS) lenbuf[tid] = lengths[b0 + tid];
    for (int idx = tid; idx < (int)(sizeof(Ah) / 4); idx += 512)
        ((int*)Ah)[idx] = 0;

    // Static A-frags of W_hh for this wave's 16-col slice:
    // A[m=r16][k=kc*32+q*8+j] = W_hh[c0 + r16][kc*32 + q*8 + j]. 16 VGPRs.
    f16x8 Wf[4];
    {
        const float* wrow = W_hh + (c0 + r16) * HIDDEN + q * 8;
#pragma unroll
        for (int kc = 0; kc < 4; ++kc) {
            const float* p = wrow + kc * 32;
#pragma unroll
            for (int j = 0; j < 8; ++j) Wf[kc][j] = (_Float16)p[j];
        }
    }

    __syncthreads();

    const int mylen = lenbuf[r4];
    int lenmax = 0;
#pragma unroll
    for (int r = 0; r < ROWS; ++r) lenmax = max(lenmax, lenbuf[r]);

    // Seed pipeline (all LDS): seed for step t prefetched during step t-1.
    int tok = xs[r4][0];
    f16x4 sd = *(const f16x4*)&ew[tok][c0 + 4 * q];
    int tok1 = xs[r4][1];

    int cur = 0;
    f32x4 cap = {0.f, 0.f, 0.f, 0.f};

    for (int t = 0; t < lenmax; ++t) {
        // h B-frags: B[k][n=r16] = h[r4][k]  (4-way same-address broadcast).
        const _Float16* hb = &Ah[cur][r4][q * 8];
        f16x8 H0 = *(const f16x8*)(hb + 0);
        f16x8 H1 = *(const f16x8*)(hb + 32);
        f16x8 H2 = *(const f16x8*)(hb + 64);
        f16x8 H3 = *(const f16x8*)(hb + 96);

        // Prefetch seed for t+1 and token for t+2 (LDS only).
        f16x4 sn = *(const f16x4*)&ew[tok1][c0 + 4 * q];
        const int t2 = (t + 2 < SEQ) ? t + 2 : SEQ - 1;
        const int tok2 = xs[r4][t2];

        // 2 independent 2-deep MFMA chains, seeded with embW (f16->f32).
        f32x4 a = {(float)sd[0], (float)sd[1], (float)sd[2], (float)sd[3]};
        f32x4 d = {0.f, 0.f, 0.f, 0.f};
        a = __builtin_amdgcn_mfma_f32_16x16x32_f16(Wf[0], H0, a, 0, 0, 0);
        d = __builtin_amdgcn_mfma_f32_16x16x32_f16(Wf[2], H2, d, 0, 0, 0);
        a = __builtin_amdgcn_mfma_f32_16x16x32_f16(Wf[1], H1, a, 0, 0, 0);
        d = __builtin_amdgcn_mfma_f32_16x16x32_f16(Wf[3], H3, d, 0, 0, 0);
        f32x4 z = a + d;

        f32x4 th;
        th[0] = fast_tanh(z[0]);
        th[1] = fast_tanh(z[1]);
        th[2] = fast_tanh(z[2]);
        th[3] = fast_tanh(z[3]);
        if (t + 1 == mylen) cap = th;

        uint2 pk;
        pk.x = __builtin_bit_cast(unsigned int, __builtin_amdgcn_cvt_pkrtz(th[0], th[1]));
        pk.y = __builtin_bit_cast(unsigned int, __builtin_amdgcn_cvt_pkrtz(th[2], th[3]));

        const int nxt = cur ^ 1;
        if (r16 < ROWS)  // one writer per (row, col-quad); aliased lanes hold identical data
            *(uint2*)&Ah[nxt][r16][c0 + 4 * q] = pk;
        __syncthreads();
        cur = nxt;
        sd = sn;
        tok1 = tok2;
    }

    // Final h (fp32 captures) -> hfin, then FC epilogue.
    if (r16 < ROWS)
        *(f32x4*)&hfin[r16][c0 + 4 * q] = cap;
    __syncthreads();

    // FC: thread (r, c) computes out[b0+r][c].  512 = 4 rows x 128 slots.
    const int r = tid >> 7;      // 0..3
    const int c = tid & 127;     // 0..127
    if (c < VOCAB) {
        const float4* hv = (const float4*)hfin[r];
        const float4* wf = (const float4*)(W_fc + c * HIDDEN);
        float a0 = 0.f, a1 = 0.f, a2 = 0.f, a3 = 0.f;
#pragma unroll
        for (int j = 0; j < HIDDEN / 4; ++j) {
            float4 h = hv[j];
            float4 w = wf[j];
            a0 += h.x * w.x; a1 += h.y * w.y; a2 += h.z * w.z; a3 += h.w * w.w;
        }
        out[(b0 + r) * VOCAB + c] = (a0 + a1) + (a2 + a3) + b_fc[c];
    }
}

extern "C" void kernel_launch(void* const* d_in, const int* in_sizes, int n_in,
                              void* d_out, int out_size, void* d_ws, size_t ws_size,
                              hipStream_t stream) {
    const int* x = (const int*)d_in[0];          // [B, T] int32
    const int* lengths = (const int*)d_in[1];    // [B] int32
    const float* emb = (const float*)d_in[2];    // [V, H]
    const float* W_ih = (const float*)d_in[3];   // [H, H]
    const float* W_hh = (const float*)d_in[4];   // [H, H]
    const float* W_fc = (const float*)d_in[5];   // [V, H]
    const float* b_fc = (const float*)d_in[6];   // [V]
    float* out = (float*)d_out;                  // [B, V]

    float* embW = (float*)d_ws;                  // VOCAB*HIDDEN floats (30 KB)

    rnn_prep_embw<<<VOCAB, HIDDEN, 0, stream>>>(emb, W_ih, embW);
    rnn_mfma<<<BATCH / ROWS, 512, 0, stream>>>(x, lengths, embW, W_hh, W_fc, b_fc, out);
}